// Round 9
// baseline (4296.934 us; speedup 1.0000x reference)
//
#include <hip/hip_runtime.h>
#include <math.h>

#define IN_DIM 8192
#define HID 128
#define NSTEPS 4096

typedef _Float16 f16x8 __attribute__((ext_vector_type(8)));
typedef float f32x4 __attribute__((ext_vector_type(4)));

__device__ __forceinline__ float sigm(float x) { return 1.f / (1.f + __expf(-x)); }
__device__ __forceinline__ float tanh_f(float x) {
    x = fminf(fmaxf(x, -15.f), 15.f);          // avoid inf/inf NaN
    float e = __expf(2.f * x);
    return (e - 1.f) / (e + 1.f);
}

// ---------------------------------------------------------------------------
// Kernel 1: M = W_enc @ W_dec  (128x128), cvec = W_enc@b_dec + b_enc,
//           e1 = W_enc@x0 + b_enc.  Grid: 128 blocks (one per row p), 128 thr.
// ---------------------------------------------------------------------------
__global__ __launch_bounds__(128) void k_precompute_M(
    const float* __restrict__ W_enc, const float* __restrict__ W_dec,
    const float* __restrict__ b_enc, const float* __restrict__ b_dec,
    const float* __restrict__ x0,
    float* __restrict__ M, float* __restrict__ cvec, float* __restrict__ e1)
{
    const int p = blockIdx.x;
    const int t = threadIdx.x;              // 0..127 (= output column q)
    __shared__ float wl[128];
    __shared__ float red[256];
    float m0 = 0.f, m1 = 0.f, m2 = 0.f, m3 = 0.f, cacc = 0.f, eacc = 0.f;
    for (int i0 = 0; i0 < IN_DIM; i0 += 128) {
        float w = W_enc[(size_t)p * IN_DIM + i0 + t];   // coalesced
        cacc = fmaf(w, b_dec[i0 + t], cacc);
        eacc = fmaf(w, x0[i0 + t], eacc);
        wl[t] = w;
        __syncthreads();
#pragma unroll 8
        for (int k = 0; k < 128; k += 4) {              // W_dec reads coalesced in t
            m0 = fmaf(wl[k],     W_dec[(size_t)(i0 + k) * HID + t], m0);
            m1 = fmaf(wl[k + 1], W_dec[(size_t)(i0 + k + 1) * HID + t], m1);
            m2 = fmaf(wl[k + 2], W_dec[(size_t)(i0 + k + 2) * HID + t], m2);
            m3 = fmaf(wl[k + 3], W_dec[(size_t)(i0 + k + 3) * HID + t], m3);
        }
        __syncthreads();
    }
    M[p * HID + t] = (m0 + m1) + (m2 + m3);
    red[t] = cacc; red[128 + t] = eacc;
    __syncthreads();
    for (int s = 64; s > 0; s >>= 1) {
        if (t < s) { red[t] += red[t + s]; red[128 + t] += red[128 + t + s]; }
        __syncthreads();
    }
    if (t == 0) { cvec[p] = red[0] + b_enc[p]; e1[p] = red[128] + b_enc[p]; }
}

// ---------------------------------------------------------------------------
// Kernel 2: G rows 0..383 = W_ih@M, rows 384..767 = W_hh (copy).
//           gb[0..383] = W_ih@cvec + bias, gb[384..767] = 0.
//           ig1 = W_ih@e1 + bias.  Grid: 768 blocks, 128 threads.
// ---------------------------------------------------------------------------
__global__ __launch_bounds__(128) void k_precompute_G(
    const float* __restrict__ W_ih, const float* __restrict__ W_hh,
    const float* __restrict__ bias, const float* __restrict__ M,
    const float* __restrict__ cvec, const float* __restrict__ e1,
    float* __restrict__ G, float* __restrict__ gb, float* __restrict__ ig1)
{
    const int r = blockIdx.x;
    const int q = threadIdx.x;
    if (r >= 384) {
        G[(size_t)r * HID + q] = W_hh[(size_t)(r - 384) * HID + q];
        if (q == 0) gb[r] = 0.f;
        return;
    }
    __shared__ float red[256];
    float a0 = 0.f, a1 = 0.f, a2 = 0.f, a3 = 0.f;
#pragma unroll 8
    for (int k = 0; k < HID; k += 4) {   // W_ih[r][k] scalar-uniform, M coalesced
        a0 = fmaf(W_ih[r * HID + k],     M[(k) * HID + q], a0);
        a1 = fmaf(W_ih[r * HID + k + 1], M[(k + 1) * HID + q], a1);
        a2 = fmaf(W_ih[r * HID + k + 2], M[(k + 2) * HID + q], a2);
        a3 = fmaf(W_ih[r * HID + k + 3], M[(k + 3) * HID + q], a3);
    }
    G[(size_t)r * HID + q] = (a0 + a1) + (a2 + a3);
    float wq = W_ih[r * HID + q];
    red[q] = wq * cvec[q];
    red[128 + q] = wq * e1[q];
    __syncthreads();
    for (int s = 64; s > 0; s >>= 1) {
        if (q < s) { red[q] += red[q + s]; red[128 + q] += red[128 + q + s]; }
        __syncthreads();
    }
    if (q == 0) { gb[r] = red[0] + bias[r]; ig1[r] = red[128] + bias[r]; }
}

// ---------------------------------------------------------------------------
// Kernel 2b: pack G (f32, 768x128 row-major) into MFMA A-fragments (f16).
// Fragment (w,j,c): wave w, tile j (rows 48w+16j..+15), K-chunk c (k=32c..+31).
// A-layout for v_mfma_f32_16x16x32_f16: lane l holds A[row=l&15][k=(l>>4)*8+i].
// ---------------------------------------------------------------------------
__global__ __launch_bounds__(256) void k_pack(
    const float* __restrict__ G, _Float16* __restrict__ Gp)
{
    int id = blockIdx.x * 256 + threadIdx.x;   // 0..98303
    int i = id & 7;
    int l = (id >> 3) & 63;
    int frag = id >> 9;                        // 0..191 = w*12 + j*4 + c
    int c = frag & 3;
    int j = (frag >> 2) % 3;
    int w = frag / 12;
    int row = 48 * w + 16 * j + (l & 15);
    int k = 32 * c + ((l >> 4) << 3) + i;
    Gp[id] = (_Float16)G[row * HID + k];
}

// ---------------------------------------------------------------------------
// Kernel 3: sequential GRU scan via MFMA. ONE block, 1024 threads (16 waves).
// Weights stationary as 12 MFMA A-fragments in AGPRs (R8-verified resident:
// FETCH halved, VGPR 48+48 AGPR = 96 <= 128 unified budget).
// R8 lesson: step was 2000 cyc vs ~400 of work -> serialization. Biggest
// serial item: compiler emits s_waitcnt vmcnt(0) before every s_barrier
// (m97-documented), so the gate wave's per-step global H-store had to
// COMPLETE before anyone crossed barrier 2. Fix: raw s_barrier + explicit
// lgkmcnt(0) only (HK m194-m201 pattern) -> the H store floats (distinct
// addresses, drained at kernel end). Also: MFMA chains split 4-deep -> 2+2
// (paired accumulators), halving matrix-pipe chain latency.
// ---------------------------------------------------------------------------
#define WF(F) F(0,0) F(0,1) F(0,2) F(0,3) F(1,0) F(1,1) F(1,2) F(1,3) \
              F(2,0) F(2,1) F(2,2) F(2,3)

__global__ __launch_bounds__(1024, 4) void k_recurrence(
    const _Float16* __restrict__ Gp, const float* __restrict__ gb,
    const float* __restrict__ ig1, const float* __restrict__ bias_n,
    float* __restrict__ H)
{
    const int t = threadIdx.x;           // 0..1023
    const int l = t & 63;                // lane
    const int w = t >> 6;                // wave 0..15; rows 48w..48w+47
    __shared__ _Float16 h16[HID];        // 256 B, single copy (broadcast reads)
    __shared__ float g_lds[6 * HID];
    __shared__ float gb_lds[6 * HID];

    if (t < 6 * HID) gb_lds[t] = gb[t];

    // --- stationary weights: 12 MFMA A-fragments -> AGPRs ---
    const f16x8* gpb = (const f16x8*)Gp;
#define DECLW(j,c) f16x8 wf##j##c = gpb[(w * 12 + j * 4 + c) * 64 + l];
    WF(DECLW)
#undef DECLW
#define PINW(j,c) asm volatile("" : "+a"(wf##j##c));
    WF(PINW)
#undef PINW

    const float bnr = (t < HID) ? bias_n[t] : 0.f;
    float hreg = 0.f;

    // step 1: h0 = 0 => hg = 0, use precomputed ig1
    if (t < HID) {
        float ir = ig1[t], iz = ig1[HID + t], inn = ig1[2 * HID + t];
        float rg = sigm(ir), zg = sigm(iz);
        float ng = tanh_f(fmaf(rg, bnr, inn));
        hreg = ng - zg * ng;             // n + z*(0 - n)
        h16[t] = (_Float16)hreg;
        H[t] = hreg;
    }
    __syncthreads();

    const int g4 = l >> 4;                       // 16-lane group 0..3
    const char* hbase = (const char*)h16 + g4 * 16;
    const int pbase = 48 * w + (g4 << 2);        // g-write row base (j=0)
    const float4 gbv0 = *(const float4*)&gb_lds[pbase];
    const float4 gbv1 = *(const float4*)&gb_lds[pbase + 16];
    const float4 gbv2 = *(const float4*)&gb_lds[pbase + 32];
    const bool writer = (l & 15) == 0;
    const f32x4 zero = {0.f, 0.f, 0.f, 0.f};

    for (int st = 1; st < NSTEPS; ++st) {
        // B-fragments: h chunk c, lane l -> h[32c + 8*(l>>4) + i] (16B bcast)
        f16x8 b0 = *(const f16x8*)(hbase);
        f16x8 b1 = *(const f16x8*)(hbase + 64);
        f16x8 b2 = *(const f16x8*)(hbase + 128);
        f16x8 b3 = *(const f16x8*)(hbase + 192);
        // split accumulator pairs: chain depth 2 instead of 4
        f32x4 d0a = __builtin_amdgcn_mfma_f32_16x16x32_f16(wf00, b0, zero, 0, 0, 0);
        f32x4 d1a = __builtin_amdgcn_mfma_f32_16x16x32_f16(wf10, b0, zero, 0, 0, 0);
        f32x4 d2a = __builtin_amdgcn_mfma_f32_16x16x32_f16(wf20, b0, zero, 0, 0, 0);
        f32x4 d0b = __builtin_amdgcn_mfma_f32_16x16x32_f16(wf01, b1, zero, 0, 0, 0);
        f32x4 d1b = __builtin_amdgcn_mfma_f32_16x16x32_f16(wf11, b1, zero, 0, 0, 0);
        f32x4 d2b = __builtin_amdgcn_mfma_f32_16x16x32_f16(wf21, b1, zero, 0, 0, 0);
        d0a = __builtin_amdgcn_mfma_f32_16x16x32_f16(wf02, b2, d0a, 0, 0, 0);
        d1a = __builtin_amdgcn_mfma_f32_16x16x32_f16(wf12, b2, d1a, 0, 0, 0);
        d2a = __builtin_amdgcn_mfma_f32_16x16x32_f16(wf22, b2, d2a, 0, 0, 0);
        d0b = __builtin_amdgcn_mfma_f32_16x16x32_f16(wf03, b3, d0b, 0, 0, 0);
        d1b = __builtin_amdgcn_mfma_f32_16x16x32_f16(wf13, b3, d1b, 0, 0, 0);
        d2b = __builtin_amdgcn_mfma_f32_16x16x32_f16(wf23, b3, d2b, 0, 0, 0);
        if (writer) {                    // lanes 0,16,32,48: rows pbase..+3
            float4 v0 = { d0a[0] + d0b[0] + gbv0.x, d0a[1] + d0b[1] + gbv0.y,
                          d0a[2] + d0b[2] + gbv0.z, d0a[3] + d0b[3] + gbv0.w };
            float4 v1 = { d1a[0] + d1b[0] + gbv1.x, d1a[1] + d1b[1] + gbv1.y,
                          d1a[2] + d1b[2] + gbv1.z, d1a[3] + d1b[3] + gbv1.w };
            float4 v2 = { d2a[0] + d2b[0] + gbv2.x, d2a[1] + d2b[1] + gbv2.y,
                          d2a[2] + d2b[2] + gbv2.z, d2a[3] + d2b[3] + gbv2.w };
            *(float4*)&g_lds[pbase]      = v0;
            *(float4*)&g_lds[pbase + 16] = v1;
            *(float4*)&g_lds[pbase + 32] = v2;
        }
        // LDS-visibility-only barrier: do NOT drain vmcnt (H stores float)
        asm volatile("s_waitcnt lgkmcnt(0)" ::: "memory");
        __builtin_amdgcn_s_barrier();
        if (t < HID) {                   // waves 0,1 only; uniform branch
            float ir = g_lds[t],           iz = g_lds[HID + t],     inn = g_lds[2 * HID + t];
            float hr = g_lds[3 * HID + t], hz = g_lds[4 * HID + t], hn = g_lds[5 * HID + t];
            float rg = sigm(ir + hr);
            float zg = sigm(iz + hz);
            float ng = tanh_f(inn + rg * (hn + bnr));
            float hnew = ng + zg * (hreg - ng);
            hreg = hnew;
            h16[t] = (_Float16)hnew;
            H[(size_t)st * HID + t] = hnew;   // never drained in-loop
        }
        asm volatile("s_waitcnt lgkmcnt(0)" ::: "memory");
        __builtin_amdgcn_s_barrier();
    }
}

// ---------------------------------------------------------------------------
// Kernel 4: out[t][i] = dot(H[t][:], W_dec[i][:]) + b_dec[i]
// GEMM M=4096(t) N=8192(i) K=128, fp32 vector. 64x64 tiles, 256 threads,
// 4x4 micro-tile (strided by 16), XOR-swizzled LDS (64KB total, conflict-free).
// ---------------------------------------------------------------------------
__global__ __launch_bounds__(256) void k_decode(
    const float* __restrict__ H, const float* __restrict__ W_dec,
    const float* __restrict__ b_dec, float* __restrict__ out)
{
    __shared__ float4 As[64 * 32];   // [t][k4], k4 XOR-swizzled by (t&7)
    __shared__ float4 Bs[64 * 32];   // [i][k4]
    const int tid = threadIdx.x;
    const int t0 = blockIdx.y * 64;
    const int i0 = blockIdx.x * 64;
#pragma unroll 8
    for (int j = 0; j < 8; ++j) {
        int f = tid + 256 * j;        // 0..2047 float4s, coalesced
        int t = f >> 5;
        int k4 = f & 31;
        int sw = k4 ^ (t & 7);
        As[t * 32 + sw] = *(const float4*)(H + (size_t)(t0 + t) * HID + 4 * k4);
        Bs[t * 32 + sw] = *(const float4*)(W_dec + (size_t)(i0 + t) * HID + 4 * k4);
    }
    __syncthreads();
    const int tx = tid & 15, ty = tid >> 4;
    const int xa = ty & 7, xb = tx & 7;
    float acc[4][4] = {{0.f}};
#pragma unroll 8
    for (int k4 = 0; k4 < 32; ++k4) {
        float4 a[4], b[4];
        int ia = k4 ^ xa, ib = k4 ^ xb;
#pragma unroll
        for (int u = 0; u < 4; ++u) a[u] = As[(ty + 16 * u) * 32 + ia];
#pragma unroll
        for (int v = 0; v < 4; ++v) b[v] = Bs[(tx + 16 * v) * 32 + ib];
#pragma unroll
        for (int u = 0; u < 4; ++u)
#pragma unroll
            for (int v = 0; v < 4; ++v) {
                acc[u][v] = fmaf(a[u].x, b[v].x, acc[u][v]);
                acc[u][v] = fmaf(a[u].y, b[v].y, acc[u][v]);
                acc[u][v] = fmaf(a[u].z, b[v].z, acc[u][v]);
                acc[u][v] = fmaf(a[u].w, b[v].w, acc[u][v]);
            }
    }
#pragma unroll
    for (int u = 0; u < 4; ++u) {
        int t = t0 + ty + 16 * u;
#pragma unroll
        for (int v = 0; v < 4; ++v) {
            int i = i0 + tx + 16 * v;
            out[(size_t)t * IN_DIM + i] = acc[u][v] + b_dec[i];
        }
    }
}

// ---------------------------------------------------------------------------
extern "C" void kernel_launch(void* const* d_in, const int* in_sizes, int n_in,
                              void* d_out, int out_size, void* d_ws, size_t ws_size,
                              hipStream_t stream)
{
    const float* x0     = (const float*)d_in[0];
    const float* W_enc  = (const float*)d_in[1];
    const float* b_enc  = (const float*)d_in[2];
    const float* W_ih   = (const float*)d_in[3];
    const float* W_hh   = (const float*)d_in[4];
    const float* bias   = (const float*)d_in[5];
    const float* bias_n = (const float*)d_in[6];
    const float* W_dec  = (const float*)d_in[7];
    const float* b_dec  = (const float*)d_in[8];
    float* out = (float*)d_out;

    // workspace layout (floats): ~2.76 MB
    float* ws   = (float*)d_ws;
    float* M    = ws;                 // 16384
    float* cvec = ws + 16384;         // 128
    float* e1   = ws + 16512;         // 128
    float* ig1  = ws + 16640;         // 384
    float* gb   = ws + 17024;         // 768
    float* G    = ws + 17792;         // 98304   (16B-aligned)
    float* H    = ws + 116096;        // 524288  (16B-aligned)
    _Float16* Gp = (_Float16*)(ws + 640384);   // 98304 f16 (192 KB)

    k_precompute_M<<<128, 128, 0, stream>>>(W_enc, W_dec, b_enc, b_dec, x0, M, cvec, e1);
    k_precompute_G<<<768, 128, 0, stream>>>(W_ih, W_hh, bias, M, cvec, e1, G, gb, ig1);
    k_pack<<<384, 256, 0, stream>>>(G, Gp);
    k_recurrence<<<1, 1024, 0, stream>>>(Gp, gb, ig1, bias_n, H);
    dim3 grid(IN_DIM / 64, NSTEPS / 64);
    k_decode<<<grid, 256, 0, stream>>>(H, W_dec, b_dec, out);
}